// Round 4
// baseline (1046.891 us; speedup 1.0000x reference)
//
#include <hip/hip_runtime.h>
#include <hip/hip_bf16.h>

// ---------------------------------------------------------------------------
// VIN forward, fp32 baseline (r4).
// Stage A: conv1(3->64,3x3,pad1)+bias+maxpool2 -> pool1 (32,64,64,64)
// Stage B: bn1 stats -> (a,c); conv2 reads relu(a*x+c) on the fly
// Stage C: conv2(64->128)+pool -> pool2 (32,128,32,32); bn2 stats
// Stage D: conv3(128->128)+pool -> pool3 (32,128,16,16); bn3 stats
// Stage E: one block per image: bn3+relu -> r(1x1 conv) -> conv_r(5x5) ->
//          K VI iterations in LDS -> critic + q outputs
// r4 vs r3: conv1 computes all 64 co per block (streamed acc), grid 512
//           blocks -> input staged once instead of 4x.
// ---------------------------------------------------------------------------

// ---------------- conv1: X(32,3,128,128) -> pool1(32,64,64,64) -------------
__global__ __launch_bounds__(256)
void conv1_pool_kernel(const float* __restrict__ X, const float* __restrict__ W,
                       const float* __restrict__ Bias, float* __restrict__ out)
{
    const int sp  = blockIdx.x;          // 16 spatial tiles (4x4 of 16x16 pooled)
    const int n   = blockIdx.y;
    const int ty0 = (sp >> 2) * 16;      // pooled row origin
    const int tx0 = (sp & 3) * 16;
    const int tid = threadIdx.x;
    const int px = tid & 15, py = tid >> 4;

    __shared__ float s_in[3][34][34];    // shifted: s_in[ci][cy+dy][cx+dx]

    const int gy0 = 2 * ty0 - 1, gx0 = 2 * tx0 - 1;
    for (int idx = tid; idx < 3 * 1156; idx += 256) {
        int ci = idx / 1156, rem = idx - ci * 1156;
        int ly = rem / 34, lx = rem - ly * 34;
        int gy = gy0 + ly, gx = gx0 + lx;
        float v = 0.f;
        if ((unsigned)gy < 128u && (unsigned)gx < 128u)
            v = X[((n * 3 + ci) << 14) + (gy << 7) + gx];
        s_in[ci][ly][lx] = v;
    }
    __syncthreads();

    // register patch: input rows 2py..2py+3, cols 2px..2px+3 (shifted coords)
    float patch[3][4][4];
    #pragma unroll
    for (int ci = 0; ci < 3; ++ci)
        #pragma unroll
        for (int r = 0; r < 4; ++r) {
            float2 a = *(const float2*)&s_in[ci][2 * py + r][2 * px];
            float2 b = *(const float2*)&s_in[ci][2 * py + r][2 * px + 2];
            patch[ci][r][0] = a.x; patch[ci][r][1] = a.y;
            patch[ci][r][2] = b.x; patch[ci][r][3] = b.y;
        }

    const int out_base = ((n * 64) << 12) + (ty0 + py) * 64 + tx0 + px;
    #pragma unroll 1
    for (int co = 0; co < 64; ++co) {
        // wave-uniform weight loads -> SGPRs (27 floats, contiguous)
        float wk[27];
        const float* wp = W + co * 27;
        #pragma unroll
        for (int k = 0; k < 27; ++k) wk[k] = wp[k];
        float b0 = Bias[co];
        float a0 = b0, a1 = b0, a2 = b0, a3 = b0;
        #pragma unroll
        for (int ci = 0; ci < 3; ++ci)
            #pragma unroll
            for (int dy = 0; dy < 3; ++dy)
                #pragma unroll
                for (int dx = 0; dx < 3; ++dx) {
                    float w = wk[ci * 9 + dy * 3 + dx];
                    a0 = fmaf(w, patch[ci][dy][dx],     a0);
                    a1 = fmaf(w, patch[ci][dy][dx + 1], a1);
                    a2 = fmaf(w, patch[ci][dy + 1][dx], a2);
                    a3 = fmaf(w, patch[ci][dy + 1][dx + 1], a3);
                }
        out[out_base + (co << 12)] = fmaxf(fmaxf(a0, a1), fmaxf(a2, a3));
    }
}

// ---------------- BN stats: pooled (32,C,HW) -> a[c], c[c] -----------------
__global__ __launch_bounds__(1024)
void bn_stats_kernel(const float* __restrict__ data, const float* __restrict__ g,
                     const float* __restrict__ b, float* __restrict__ a_out,
                     float* __restrict__ c_out, int C, int HW)
{
    const int c = blockIdx.x;
    const int tid = threadIdx.x;
    const int nthr = blockDim.x;
    float s = 0.f, s2 = 0.f;
    for (int n = 0; n < 32; ++n) {
        const float* p = data + (size_t)(n * C + c) * HW;
        for (int i = tid * 4; i < HW; i += 4 * nthr) {
            float4 v = *(const float4*)(p + i);
            s  += v.x + v.y + v.z + v.w;
            s2 += v.x * v.x + v.y * v.y + v.z * v.z + v.w * v.w;
        }
    }
    __shared__ float rs[1024], rs2[1024];
    rs[tid] = s; rs2[tid] = s2;
    __syncthreads();
    for (int off = nthr >> 1; off > 0; off >>= 1) {
        if (tid < off) { rs[tid] += rs[tid + off]; rs2[tid] += rs2[tid + off]; }
        __syncthreads();
    }
    if (tid == 0) {
        float cnt = 32.f * (float)HW;
        float mean = rs[0] / cnt;
        float var  = rs2[0] / cnt - mean * mean;
        float a = g[c] * rsqrtf(var + 1e-5f);
        a_out[c] = a;
        c_out[c] = b[c] - mean * a;
    }
}

// ------ conv(CIN->128, 3x3 pad1) on bn-relu'd input + maxpool2 -------------
template <int CIN, int WIN, int CO_T>
__global__ __launch_bounds__(256)
void conv_bn_pool_kernel(const float* __restrict__ in, const float* __restrict__ W,
                         const float* __restrict__ Bias, const float* __restrict__ bn_a,
                         const float* __restrict__ bn_c, float* __restrict__ out)
{
    constexpr int WOUT = WIN / 2;
    constexpr int SPT  = WOUT / 16;      // spatial tiles per row
    constexpr int CI_T = 4;
    const int cot = blockIdx.x;          // co-tile of CO_T (128/CO_T tiles)
    const int sp  = blockIdx.y;
    const int n   = blockIdx.z;
    const int ty0 = (sp / SPT) * 16, tx0 = (sp % SPT) * 16;
    const int tid = threadIdx.x;
    const int px = tid & 15, py = tid >> 4;

    __shared__ float s_in[CI_T][34][34];

    float acc[CO_T][4];
    #pragma unroll
    for (int co = 0; co < CO_T; ++co) {
        float b0 = Bias[cot * CO_T + co];
        acc[co][0] = b0; acc[co][1] = b0; acc[co][2] = b0; acc[co][3] = b0;
    }

    const int gy0 = 2 * ty0 - 1, gx0 = 2 * tx0 - 1;
    const float* Wbase = W + (size_t)(cot * CO_T) * CIN * 9;

    #pragma unroll 1
    for (int ci0 = 0; ci0 < CIN; ci0 += CI_T) {
        __syncthreads();
        for (int idx = tid; idx < CI_T * 1156; idx += 256) {
            int ci = idx / 1156, rem = idx - ci * 1156;
            int ly = rem / 34, lx = rem - ly * 34;
            int gy = gy0 + ly, gx = gx0 + lx;
            float v = 0.f;
            if ((unsigned)gy < (unsigned)WIN && (unsigned)gx < (unsigned)WIN) {
                float x = in[(size_t)(n * CIN + ci0 + ci) * (WIN * WIN) + gy * WIN + gx];
                v = fmaxf(fmaf(x, bn_a[ci0 + ci], bn_c[ci0 + ci]), 0.f);
            }
            s_in[ci][ly][lx] = v;
        }
        __syncthreads();

        #pragma unroll
        for (int ci = 0; ci < CI_T; ++ci) {
            float patch[4][4];
            #pragma unroll
            for (int r = 0; r < 4; ++r) {
                float2 a = *(const float2*)&s_in[ci][2 * py + r][2 * px];
                float2 b = *(const float2*)&s_in[ci][2 * py + r][2 * px + 2];
                patch[r][0] = a.x; patch[r][1] = a.y;
                patch[r][2] = b.x; patch[r][3] = b.y;
            }
            const float* wp = Wbase + (size_t)(ci0 + ci) * 9;
            #pragma unroll
            for (int co = 0; co < CO_T; ++co) {
                // wave-uniform: 9 contiguous floats -> s_load into SGPRs
                float wk[9];
                #pragma unroll
                for (int k = 0; k < 9; ++k) wk[k] = wp[(size_t)co * CIN * 9 + k];
                #pragma unroll
                for (int dy = 0; dy < 3; ++dy)
                    #pragma unroll
                    for (int dx = 0; dx < 3; ++dx) {
                        float w = wk[dy * 3 + dx];
                        acc[co][0] = fmaf(w, patch[dy][dx],         acc[co][0]);
                        acc[co][1] = fmaf(w, patch[dy][dx + 1],     acc[co][1]);
                        acc[co][2] = fmaf(w, patch[dy + 1][dx],     acc[co][2]);
                        acc[co][3] = fmaf(w, patch[dy + 1][dx + 1], acc[co][3]);
                    }
            }
        }
    }

    const size_t out_base = (size_t)(n * 128 + cot * CO_T) * (WOUT * WOUT)
                          + (ty0 + py) * WOUT + tx0 + px;
    #pragma unroll
    for (int co = 0; co < CO_T; ++co) {
        float m = fmaxf(fmaxf(acc[co][0], acc[co][1]), fmaxf(acc[co][2], acc[co][3]));
        out[out_base + (size_t)co * (WOUT * WOUT)] = m;
    }
}

// ---------------- VIN head: one block per image ----------------------------
__global__ __launch_bounds__(256)
void vin_kernel(const float* __restrict__ pool3, const float* __restrict__ bn_a,
                const float* __restrict__ bn_c, const float* __restrict__ r_w,
                const float* __restrict__ q_w, const float* __restrict__ w_vi,
                const float* __restrict__ crit_w, const float* __restrict__ crit_b,
                const int* __restrict__ Kp, float* __restrict__ out_critic,
                float* __restrict__ out_q)
{
    const int n = blockIdx.x;
    const int tid = threadIdx.x;           // 256 = 16x16 positions
    const int px = tid & 15, py = tid >> 4;

    __shared__ float s_cr[16][256];        // conv_r[co][pos]
    __shared__ float s_v[20][20];          // padded plane (r, then v)
    __shared__ float s_qw[16][25];
    __shared__ float s_wvi[16][25];
    __shared__ float s_rw[128];
    __shared__ float s_red[256];

    for (int i = tid; i < 400; i += 256) {
        s_qw[i / 25][i % 25]  = q_w[i];
        s_wvi[i / 25][i % 25] = w_vi[i];
        s_v[i / 20][i % 20]   = 0.f;
    }
    if (tid < 128) s_rw[tid] = r_w[tid];
    __syncthreads();

    // r[pos] = sum_ci relu(bn3(pool3)) * r_w[ci]
    float r = 0.f;
    const float* p3 = pool3 + (size_t)n * 128 * 256 + tid;
    #pragma unroll 4
    for (int ci = 0; ci < 128; ++ci) {
        float x = p3[ci * 256];
        x = fmaxf(fmaf(x, bn_a[ci], bn_c[ci]), 0.f);
        r = fmaf(x, s_rw[ci], r);
    }
    s_v[py + 2][px + 2] = r;               // padded r plane
    __syncthreads();

    // conv_r = conv5x5(r, q_w), initial v = max_co conv_r
    float cr[16];
    #pragma unroll
    for (int co = 0; co < 16; ++co) cr[co] = 0.f;
    #pragma unroll
    for (int dy = 0; dy < 5; ++dy)
        #pragma unroll
        for (int dx = 0; dx < 5; ++dx) {
            float rv = s_v[py + dy][px + dx];
            #pragma unroll
            for (int co = 0; co < 16; ++co)
                cr[co] = fmaf(s_qw[co][dy * 5 + dx], rv, cr[co]);
        }
    float v = cr[0];
    #pragma unroll
    for (int co = 0; co < 16; ++co) { s_cr[co][tid] = cr[co]; v = fmaxf(v, cr[co]); }
    __syncthreads();                       // all reads of r plane done
    s_v[py + 2][px + 2] = v;
    __syncthreads();

    const int K = Kp[0];
    float q[16];
    #pragma unroll 1
    for (int it = 0; it < K; ++it) {
        #pragma unroll
        for (int co = 0; co < 16; ++co) q[co] = s_cr[co][tid];
        #pragma unroll
        for (int dy = 0; dy < 5; ++dy)
            #pragma unroll
            for (int dx = 0; dx < 5; ++dx) {
                float vv = s_v[py + dy][px + dx];
                #pragma unroll
                for (int co = 0; co < 16; ++co)
                    q[co] = fmaf(s_wvi[co][dy * 5 + dx], vv, q[co]);
            }
        float nv = q[0];
        #pragma unroll
        for (int co = 1; co < 16; ++co) nv = fmaxf(nv, q[co]);
        __syncthreads();                   // all reads of old v done
        s_v[py + 2][px + 2] = nv;
        __syncthreads();                   // new v visible
        v = nv;
    }

    // q output: (B, 16, 16, 16) -> flat 4096 per image
    #pragma unroll
    for (int co = 0; co < 16; ++co)
        out_q[(size_t)n * 4096 + co * 256 + tid] = q[co];

    // critic[n] = sum_pos v*crit_w + crit_b
    s_red[tid] = v * crit_w[tid];
    __syncthreads();
    for (int off = 128; off > 0; off >>= 1) {
        if (tid < off) s_red[tid] += s_red[tid + off];
        __syncthreads();
    }
    if (tid == 0) out_critic[n] = s_red[0] + crit_b[0];
}

// ---------------------------------------------------------------------------
extern "C" void kernel_launch(void* const* d_in, const int* in_sizes, int n_in,
                              void* d_out, int out_size, void* d_ws, size_t ws_size,
                              hipStream_t stream)
{
    const float* X      = (const float*)d_in[0];
    // d_in[1] = obs (unused)
    const float* h1_w   = (const float*)d_in[2];
    const float* h1_b   = (const float*)d_in[3];
    const float* bn1_g  = (const float*)d_in[4];
    const float* bn1_b  = (const float*)d_in[5];
    const float* h2_w   = (const float*)d_in[6];
    const float* h2_b   = (const float*)d_in[7];
    const float* bn2_g  = (const float*)d_in[8];
    const float* bn2_b  = (const float*)d_in[9];
    const float* h3_w   = (const float*)d_in[10];
    const float* h3_b   = (const float*)d_in[11];
    const float* bn3_g  = (const float*)d_in[12];
    const float* bn3_b  = (const float*)d_in[13];
    const float* r_w    = (const float*)d_in[14];
    const float* q_w    = (const float*)d_in[15];
    const float* w_vi   = (const float*)d_in[16];
    const float* crit_w = (const float*)d_in[17];
    const float* crit_b = (const float*)d_in[18];
    const int*   Kp     = (const int*)d_in[19];

    float* ws    = (float*)d_ws;
    float* pool1 = ws;                         // 32*64*64*64   = 8388608
    float* pool2 = pool1 + 8388608;            // 32*128*32*32  = 4194304
    float* pool3 = pool2 + 4194304;            // 32*128*16*16  = 1048576
    float* bn1a  = pool3 + 1048576;
    float* bn1c  = bn1a + 64;
    float* bn2a  = bn1c + 64;
    float* bn2c  = bn2a + 128;
    float* bn3a  = bn2c + 128;
    float* bn3c  = bn3a + 128;

    float* out_critic = (float*)d_out;         // 32
    float* out_q      = out_critic + 32;       // 32*4096

    conv1_pool_kernel<<<dim3(16, 32), 256, 0, stream>>>(X, h1_w, h1_b, pool1);
    bn_stats_kernel<<<64, 1024, 0, stream>>>(pool1, bn1_g, bn1_b, bn1a, bn1c, 64, 4096);
    conv_bn_pool_kernel<64, 64, 16><<<dim3(8, 4, 32), 256, 0, stream>>>(
        pool1, h2_w, h2_b, bn1a, bn1c, pool2);
    bn_stats_kernel<<<128, 1024, 0, stream>>>(pool2, bn2_g, bn2_b, bn2a, bn2c, 128, 1024);
    conv_bn_pool_kernel<128, 32, 8><<<dim3(16, 1, 32), 256, 0, stream>>>(
        pool2, h3_w, h3_b, bn2a, bn2c, pool3);
    bn_stats_kernel<<<128, 1024, 0, stream>>>(pool3, bn3_g, bn3_b, bn3a, bn3c, 128, 256);
    vin_kernel<<<32, 256, 0, stream>>>(pool3, bn3a, bn3c, r_w, q_w, w_vi,
                                       crit_w, crit_b, Kp, out_critic, out_q);
}